// Round 2
// baseline (47.086 us; speedup 1.0000x reference)
//
#include <hip/hip_runtime.h>

// NTfm3D: out[b,i,h,w] = sum_k masks[b,k,h,w] * (R[b,k,i,:] . points[b,:,h,w] + t[b,k,i])
// Shapes: points (B,3,H,W) f32, masks (B,K,H,W) f32, transforms (B,K,3,4) f32
// B=16, K=8, H=480, W=640. Memory-bound: 56 B/pixel, ~276 MB total.
// R1: 8 pixels/thread (2x float4 per stream) for doubled per-wave MLP.

constexpr int B_ = 16;
constexpr int K_ = 8;
constexpr int H_ = 480;
constexpr int W_ = 640;
constexpr int HW_ = H_ * W_;          // 307200
constexpr int VEC = 4;
constexpr int UNROLL = 2;             // two float4 segments per thread
constexpr int BLOCK = 256;
constexpr int PIX_PER_BLOCK = BLOCK * VEC * UNROLL;   // 2048
constexpr int BLOCKS_PER_B = HW_ / PIX_PER_BLOCK;     // 150

__global__ __launch_bounds__(BLOCK) void ntfm3d_kernel(
    const float* __restrict__ points,      // (B,3,H,W)
    const float* __restrict__ masks,       // (B,K,H,W)
    const float* __restrict__ transforms,  // (B,K,3,4)
    float* __restrict__ out)               // (B,3,H,W)
{
    __shared__ float tf[K_ * 12];  // [k][i*4+j], j=0..2 -> R row, j=3 -> t

    const int b = blockIdx.y;

    if (threadIdx.x < K_ * 12) {
        tf[threadIdx.x] = transforms[(size_t)b * K_ * 12 + threadIdx.x];
    }
    __syncthreads();

    // segment u covers pixels [blockbase + u*1024 + tid*4, +4)
    const int blockbase = blockIdx.x * PIX_PER_BLOCK;
    const int p0 = blockbase + threadIdx.x * VEC;

    const float* pp = points + (size_t)b * 3 * HW_;
    const float* mp = masks  + (size_t)b * K_ * HW_;

    float4 x[UNROLL], y[UNROLL], z[UNROLL];
    float4 m[K_][UNROLL];

    // Stage all loads first (static indices -> registers, max MLP).
#pragma unroll
    for (int u = 0; u < UNROLL; ++u) {
        const int p = p0 + u * BLOCK * VEC;
        x[u] = *reinterpret_cast<const float4*>(pp + p);
        y[u] = *reinterpret_cast<const float4*>(pp + HW_ + p);
        z[u] = *reinterpret_cast<const float4*>(pp + 2 * HW_ + p);
    }
#pragma unroll
    for (int k = 0; k < K_; ++k) {
#pragma unroll
        for (int u = 0; u < UNROLL; ++u) {
            const int p = p0 + u * BLOCK * VEC;
            m[k][u] = *reinterpret_cast<const float4*>(mp + (size_t)k * HW_ + p);
        }
    }

    float4 acc0[UNROLL], acc1[UNROLL], acc2[UNROLL];
#pragma unroll
    for (int u = 0; u < UNROLL; ++u) {
        acc0[u] = {0.f, 0.f, 0.f, 0.f};
        acc1[u] = {0.f, 0.f, 0.f, 0.f};
        acc2[u] = {0.f, 0.f, 0.f, 0.f};
    }

#pragma unroll
    for (int k = 0; k < K_; ++k) {
        const float* T = tf + k * 12;
        const float r00 = T[0], r01 = T[1], r02 = T[2],  t0 = T[3];
        const float r10 = T[4], r11 = T[5], r12 = T[6],  t1 = T[7];
        const float r20 = T[8], r21 = T[9], r22 = T[10], t2 = T[11];

#pragma unroll
        for (int u = 0; u < UNROLL; ++u) {
#define APPLY(c)                                                                   \
            {                                                                      \
                float s0 = fmaf(r00, x[u].c, fmaf(r01, y[u].c, fmaf(r02, z[u].c, t0))); \
                float s1 = fmaf(r10, x[u].c, fmaf(r11, y[u].c, fmaf(r12, z[u].c, t1))); \
                float s2 = fmaf(r20, x[u].c, fmaf(r21, y[u].c, fmaf(r22, z[u].c, t2))); \
                acc0[u].c = fmaf(m[k][u].c, s0, acc0[u].c);                        \
                acc1[u].c = fmaf(m[k][u].c, s1, acc1[u].c);                        \
                acc2[u].c = fmaf(m[k][u].c, s2, acc2[u].c);                        \
            }
            APPLY(x) APPLY(y) APPLY(z) APPLY(w)
#undef APPLY
        }
    }

    float* op = out + (size_t)b * 3 * HW_;
#pragma unroll
    for (int u = 0; u < UNROLL; ++u) {
        const int p = p0 + u * BLOCK * VEC;
        *reinterpret_cast<float4*>(op + p)          = acc0[u];
        *reinterpret_cast<float4*>(op + HW_ + p)    = acc1[u];
        *reinterpret_cast<float4*>(op + 2*HW_ + p)  = acc2[u];
    }
}

extern "C" void kernel_launch(void* const* d_in, const int* in_sizes, int n_in,
                              void* d_out, int out_size, void* d_ws, size_t ws_size,
                              hipStream_t stream) {
    const float* points     = (const float*)d_in[0];
    const float* masks      = (const float*)d_in[1];
    const float* transforms = (const float*)d_in[2];
    float* out              = (float*)d_out;

    dim3 grid(BLOCKS_PER_B, B_);
    dim3 block(BLOCK);
    ntfm3d_kernel<<<grid, block, 0, stream>>>(points, masks, transforms, out);
}

// Round 4
// 44.784 us; speedup vs baseline: 1.0514x; 1.0514x over previous
//
#include <hip/hip_runtime.h>

// NTfm3D: out[b,i,h,w] = sum_k masks[b,k,h,w] * (R[b,k,i,:] . points[b,:,h,w] + t[b,k,i])
// Shapes: points (B,3,H,W) f32, masks (B,K,H,W) f32, transforms (B,K,3,4) f32
// B=16, K=8, H=480, W=640. Memory-bound: 56 B/pixel, ~276 MB total.
// R3: R0 structure + NON-TEMPORAL stores (output never re-read -> skip L3
//     allocation so the 194 MB input set stays L3-resident across replays).
//     Fix vs R2: __builtin_nontemporal_store needs a clang ext_vector type,
//     not HIP's float4 class.

typedef float f32x4 __attribute__((ext_vector_type(4)));

constexpr int B_ = 16;
constexpr int K_ = 8;
constexpr int H_ = 480;
constexpr int W_ = 640;
constexpr int HW_ = H_ * W_;          // 307200, divisible by 4
constexpr int VEC = 4;
constexpr int BLOCK = 256;
constexpr int PIX_PER_BLOCK = BLOCK * VEC;   // 1024
constexpr int BLOCKS_PER_B = HW_ / PIX_PER_BLOCK;  // 300

__global__ __launch_bounds__(BLOCK) void ntfm3d_kernel(
    const float* __restrict__ points,      // (B,3,H,W)
    const float* __restrict__ masks,       // (B,K,H,W)
    const float* __restrict__ transforms,  // (B,K,3,4)
    float* __restrict__ out)               // (B,3,H,W)
{
    __shared__ float tf[K_ * 12];  // [k][i*4+j], j=0..2 -> R row, j=3 -> t

    const int b = blockIdx.y;

    if (threadIdx.x < K_ * 12) {
        tf[threadIdx.x] = transforms[(size_t)b * K_ * 12 + threadIdx.x];
    }
    __syncthreads();

    const int p = (blockIdx.x * BLOCK + threadIdx.x) * VEC;  // pixel index in plane

    const float* pp = points + (size_t)b * 3 * HW_ + p;
    const f32x4 x = *reinterpret_cast<const f32x4*>(pp);
    const f32x4 y = *reinterpret_cast<const f32x4*>(pp + HW_);
    const f32x4 z = *reinterpret_cast<const f32x4*>(pp + 2 * HW_);

    f32x4 acc0 = {0.f, 0.f, 0.f, 0.f};
    f32x4 acc1 = {0.f, 0.f, 0.f, 0.f};
    f32x4 acc2 = {0.f, 0.f, 0.f, 0.f};

    const float* mp = masks + (size_t)b * K_ * HW_ + p;

#pragma unroll
    for (int k = 0; k < K_; ++k) {
        const f32x4 m = *reinterpret_cast<const f32x4*>(mp + (size_t)k * HW_);
        const float* T = tf + k * 12;
        const float r00 = T[0], r01 = T[1], r02 = T[2],  t0 = T[3];
        const float r10 = T[4], r11 = T[5], r12 = T[6],  t1 = T[7];
        const float r20 = T[8], r21 = T[9], r22 = T[10], t2 = T[11];

#pragma unroll
        for (int c = 0; c < 4; ++c) {
            const float s0 = fmaf(r00, x[c], fmaf(r01, y[c], fmaf(r02, z[c], t0)));
            const float s1 = fmaf(r10, x[c], fmaf(r11, y[c], fmaf(r12, z[c], t1)));
            const float s2 = fmaf(r20, x[c], fmaf(r21, y[c], fmaf(r22, z[c], t2)));
            acc0[c] = fmaf(m[c], s0, acc0[c]);
            acc1[c] = fmaf(m[c], s1, acc1[c]);
            acc2[c] = fmaf(m[c], s2, acc2[c]);
        }
    }

    float* op = out + (size_t)b * 3 * HW_ + p;
    __builtin_nontemporal_store(acc0, reinterpret_cast<f32x4*>(op));
    __builtin_nontemporal_store(acc1, reinterpret_cast<f32x4*>(op + HW_));
    __builtin_nontemporal_store(acc2, reinterpret_cast<f32x4*>(op + 2 * HW_));
}

extern "C" void kernel_launch(void* const* d_in, const int* in_sizes, int n_in,
                              void* d_out, int out_size, void* d_ws, size_t ws_size,
                              hipStream_t stream) {
    const float* points     = (const float*)d_in[0];
    const float* masks      = (const float*)d_in[1];
    const float* transforms = (const float*)d_in[2];
    float* out              = (float*)d_out;

    dim3 grid(BLOCKS_PER_B, B_);
    dim3 block(BLOCK);
    ntfm3d_kernel<<<grid, block, 0, stream>>>(points, masks, transforms, out);
}